// Round 2
// baseline (837.830 us; speedup 1.0000x reference)
//
#include <hip/hip_runtime.h>
#include <cstddef>

#define C_X   48      // channels in x: 3*12 env + 4*3 noise params
#define NB    8       // batch
#define NT    2048    // time
#define TT    64      // t-chunk for lats kernel

typedef float f32x4 __attribute__((ext_vector_type(4)));   // nontemporal-store-able

// ---------------------------------------------------------------------------
// Kernel 1: per-(b,c) mean over time of x  ->  means[b*48+c]
// ---------------------------------------------------------------------------
__global__ __launch_bounds__(64) void means_kernel(const float* __restrict__ x,
                                                   float* __restrict__ means,
                                                   int T) {
    int bc = blockIdx.x;                 // b*48 + c
    int b = bc / C_X, c = bc % C_X;
    float s = 0.f;
    for (int t = threadIdx.x; t < T; t += 64)
        s += x[((size_t)b * T + t) * C_X + c];
    #pragma unroll
    for (int off = 32; off > 0; off >>= 1)
        s += __shfl_down(s, off);
    if (threadIdx.x == 0) means[bc] = s / (float)T;
}

// ---------------------------------------------------------------------------
// Kernel 2: lats (mean-centered einsum), one pass.
// grid = (B, 18, T/TT), block = 128 threads (each owns one float4 of L=512).
// Each thread holds its 12 table float4s in registers, reused over TT t's.
// This round: env read from LDS as 3x ds_read_b128 (was 12x b32) to cut
// LDS-pipe issue pressure ~2x; output stores nontemporal (ext_vector_type).
// ---------------------------------------------------------------------------
__global__ __launch_bounds__(128) void lats_kernel(const float* __restrict__ x,
                                                   const float* __restrict__ table,
                                                   const float* __restrict__ means,
                                                   float* __restrict__ out,
                                                   int T) {
    const int b  = blockIdx.x;
    const int w  = blockIdx.y;           // 0..17
    const int tc = blockIdx.z;           // t-chunk
    const int i  = w / 6;                // part
    const int wl = w % 6;
    const int tid = threadIdx.x;         // 0..127
    const int l  = tid * 4;

    // table slice for this w, in registers: 12 x float4 = 48 VGPRs
    float4 tab[12];
    #pragma unroll
    for (int h = 0; h < 12; ++h)
        tab[h] = *(const float4*)&table[(((size_t)(i * 12 + h) * 18) + (i * 6 + wl)) * 512 + l];

    // centered env values for TT timesteps, staged in LDS (768 floats)
    // row stride 12 floats = 48 B (16B-aligned -> float4 reads legal)
    __shared__ float env_s[TT][12];
    for (int idx = tid; idx < TT * 12; idx += 128) {
        int tt = idx / 12, h = idx % 12;
        int t  = tc * TT + tt;
        env_s[tt][h] = x[((size_t)(b * T + t)) * C_X + i * 12 + h]
                     - means[b * C_X + i * 12 + h];
    }
    __syncthreads();

    size_t obase = (((size_t)(b * T + tc * TT)) * 18 + w) * 512 + l;
    const size_t ostride = (size_t)18 * 512;
    for (int tt = 0; tt < TT; ++tt) {
        // 3 x 16B LDS reads instead of 12 x 4B (LDS pipe was ~3x oversubscribed)
        float4 e0 = *(const float4*)&env_s[tt][0];
        float4 e1 = *(const float4*)&env_s[tt][4];
        float4 e2 = *(const float4*)&env_s[tt][8];
        float e[12] = {e0.x, e0.y, e0.z, e0.w,
                       e1.x, e1.y, e1.z, e1.w,
                       e2.x, e2.y, e2.z, e2.w};
        f32x4 acc = {0.f, 0.f, 0.f, 0.f};
        #pragma unroll
        for (int h = 0; h < 12; ++h) {
            acc.x += e[h] * tab[h].x;
            acc.y += e[h] * tab[h].y;
            acc.z += e[h] * tab[h].z;
            acc.w += e[h] * tab[h].w;
        }
        __builtin_nontemporal_store(acc, (f32x4*)&out[obase + (size_t)tt * ostride]);
    }
}

// ---------------------------------------------------------------------------
// Kernel 3: fused noise build + variable-sigma 9-tap Gaussian along T,
// reflect boundary. Sliding register window: each eps element read once
// (+ 8-element halo per t-chunk). block = 256 threads.
// thread -> (p = p_tile*PP + tid%PP, lane = tid/PP owns TC consecutive t's)
// ---------------------------------------------------------------------------
__global__ __launch_bounds__(256) void noise_kernel(const float* __restrict__ x,
                                                    const float* __restrict__ eps,
                                                    const float* __restrict__ means,
                                                    float* __restrict__ out,
                                                    int T, int P, int PP, int TC,
                                                    int ch_base) {
    const int tid   = threadIdx.x;
    const int pp    = tid % PP;
    const int lane  = tid / PP;
    const int lanes = blockDim.x / PP;
    const int b     = blockIdx.x;
    const int p     = blockIdx.y * PP + pp;
    const int t0    = (blockIdx.z * lanes + lane) * TC;

    // per-batch Gaussian weights (recomputed per thread; 9 expf, cheap)
    float sigma = fmaxf(means[b * C_X + ch_base + 2], 0.001f);
    float inv2s2 = -0.5f / (sigma * sigma);
    float w[9];
    float wsum = 0.f;
    #pragma unroll
    for (int j = 0; j < 9; ++j) {
        float k = (float)(j - 4);
        w[j] = expf(k * k * inv2s2);
        wsum += w[j];
    }
    float winv = 1.0f / wsum;
    #pragma unroll
    for (int j = 0; j < 9; ++j) w[j] *= winv;

    auto raw = [&](int tt) -> float {
        if (tt < 0)  tt = -tt;                 // reflect (edge excluded)
        if (tt >= T) tt = 2 * T - 2 - tt;
        size_t row = (size_t)(b * T + tt);
        float mu = x[row * C_X + ch_base];
        float sg = x[row * C_X + ch_base + 1];
        float ep = __builtin_nontemporal_load(&eps[row * (size_t)P + p]);
        return mu + sg * ep;
    };

    float win[9];
    #pragma unroll
    for (int j = 0; j < 8; ++j) win[j + 1] = raw(t0 - 4 + j);

    for (int t = t0; t < t0 + TC; ++t) {
        #pragma unroll
        for (int j = 0; j < 8; ++j) win[j] = win[j + 1];
        win[8] = raw(t + 4);
        float acc = 0.f;
        #pragma unroll
        for (int j = 0; j < 9; ++j) acc += w[j] * win[j];
        __builtin_nontemporal_store(acc, &out[(size_t)(b * T + t) * P + p]);
    }
}

// ---------------------------------------------------------------------------
extern "C" void kernel_launch(void* const* d_in, const int* in_sizes, int n_in,
                              void* d_out, int out_size, void* d_ws, size_t ws_size,
                              hipStream_t stream) {
    const float* x     = (const float*)d_in[0];
    const float* table = (const float*)d_in[1];
    const float* epss[4] = {(const float*)d_in[2], (const float*)d_in[3],
                            (const float*)d_in[4], (const float*)d_in[5]};
    float* out   = (float*)d_out;
    float* means = (float*)d_ws;     // 8*48 floats

    const int B = NB, T = NT;

    // 1) time-means of all 48 channels
    means_kernel<<<B * C_X, 64, 0, stream>>>(x, means, T);

    // 2) centered lats, one pass
    dim3 gl(B, 18, T / TT);
    lats_kernel<<<gl, 128, 0, stream>>>(x, table, means, out, T);

    // 3) four noise streams (stream 0: TC=8 for 4x more blocks)
    size_t off = (size_t)B * T * 18 * 512;
    const int Ps[4]  = {16, 64, 256, 1024};
    const int PPs[4] = {16, 64, 256, 256};
    const int TCs[4] = {8, 32, 64, 64};
    for (int i = 0; i < 4; ++i) {
        int P = Ps[i], PP = PPs[i], TC = TCs[i];
        int lanes = 256 / PP;
        dim3 gn(B, P / PP, T / (lanes * TC));
        noise_kernel<<<gn, 256, 0, stream>>>(x, epss[i], means, out + off,
                                             T, P, PP, TC, 36 + 3 * i);
        off += (size_t)B * T * P;
    }
}

// Round 3
// 775.802 us; speedup vs baseline: 1.0800x; 1.0800x over previous
//
#include <hip/hip_runtime.h>
#include <cstddef>

#define C_X   48      // channels in x: 3*12 env + 4*3 noise params
#define NB    8       // batch
#define NT    2048    // time
#define TTL   128     // t-chunk per lats block

typedef float f32x4 __attribute__((ext_vector_type(4)));

// ---------------------------------------------------------------------------
// Kernel 1: per-(b,c) mean over time of x  ->  means[b*48+c]
// ---------------------------------------------------------------------------
__global__ __launch_bounds__(64) void means_kernel(const float* __restrict__ x,
                                                   float* __restrict__ means,
                                                   int T) {
    int bc = blockIdx.x;                 // b*48 + c
    int b = bc / C_X, c = bc % C_X;
    float s = 0.f;
    for (int t = threadIdx.x; t < T; t += 64)
        s += x[((size_t)b * T + t) * C_X + c];
    #pragma unroll
    for (int off = 32; off > 0; off >>= 1)
        s += __shfl_down(s, off);
    if (threadIdx.x == 0) means[bc] = s / (float)T;
}

// ---------------------------------------------------------------------------
// Kernel 2 (fused): lats einsum + all 4 noise streams in one grid.
//   blocks [0, 2304): lats. decode bid -> (tc fastest, b, w slowest) so 128
//     consecutive blocks share one 24 KB table slice (L2 reuse).
//   blocks [2304, 3040): noise, float4 along p. Small blocks fill the tail.
// ---------------------------------------------------------------------------
__global__ __launch_bounds__(256) void mega_kernel(const float* __restrict__ x,
                                                   const float* __restrict__ table,
                                                   const float* __restrict__ means,
                                                   const float* __restrict__ eps0,
                                                   const float* __restrict__ eps1,
                                                   const float* __restrict__ eps2,
                                                   const float* __restrict__ eps3,
                                                   float* __restrict__ out,
                                                   int T) {
    const int tid = threadIdx.x;
    int bid = blockIdx.x;
    const int TCHUNKS = T / TTL;                       // 16
    const int LATS_BLOCKS = NB * 18 * TCHUNKS;         // 2304

    if (bid < LATS_BLOCKS) {
        // ---------------- lats ----------------
        const int tc = bid % TCHUNKS;
        const int b  = (bid / TCHUNKS) % NB;
        const int w  = bid / (TCHUNKS * NB);           // 0..17
        const int i  = w / 6;
        const int wl = w % 6;
        const int l4 = tid & 127;                      // float4 index in L
        const int th = tid >> 7;                       // 0..1: which tt half
        const int l  = l4 * 4;

        // table slice for this w, in registers: 12 x float4 = 48 VGPRs
        float4 tab[12];
        #pragma unroll
        for (int h = 0; h < 12; ++h)
            tab[h] = *(const float4*)&table[(((size_t)(i * 12 + h) * 18) + (i * 6 + wl)) * 512 + l];

        // centered env values for TTL timesteps, staged in LDS (6 KB)
        __shared__ float env_s[TTL][12];
        for (int idx = tid; idx < TTL * 12; idx += 256) {
            int tt = idx / 12, h = idx % 12;
            int t  = tc * TTL + tt;
            env_s[tt][h] = x[((size_t)(b * T + t)) * C_X + i * 12 + h]
                         - means[b * C_X + i * 12 + h];
        }
        __syncthreads();

        const int tt0 = th * (TTL / 2);
        size_t obase = (((size_t)(b * T + tc * TTL + tt0)) * 18 + w) * 512 + l;
        const size_t ostride = (size_t)18 * 512;
        for (int tt = tt0; tt < tt0 + TTL / 2; ++tt) {
            float4 e0 = *(const float4*)&env_s[tt][0];   // 3x ds_read_b128
            float4 e1 = *(const float4*)&env_s[tt][4];
            float4 e2 = *(const float4*)&env_s[tt][8];
            float e[12] = {e0.x, e0.y, e0.z, e0.w,
                           e1.x, e1.y, e1.z, e1.w,
                           e2.x, e2.y, e2.z, e2.w};
            f32x4 acc = {0.f, 0.f, 0.f, 0.f};
            #pragma unroll
            for (int h = 0; h < 12; ++h) {
                acc.x += e[h] * tab[h].x;
                acc.y += e[h] * tab[h].y;
                acc.z += e[h] * tab[h].z;
                acc.w += e[h] * tab[h].w;
            }
            __builtin_nontemporal_store(acc, (f32x4*)&out[obase]);
            obase += ostride;
        }
        return;
    }

    // ---------------- noise (float4 along p) ----------------
    bid -= LATS_BLOCKS;
    const float* eps; int P, PPv, TC, ch_base; size_t ooff;
    const size_t noise_base = (size_t)NB * T * 18 * 512;
    if (bid < 32) {                       // stream 0: P=16,  GZ=4
        eps = eps0; P = 16;   PPv = 4;   TC = 8;  ch_base = 36;
        ooff = noise_base;
    } else if (bid < 96) {                // stream 1: P=64,  GZ=8
        bid -= 32;
        eps = eps1; P = 64;   PPv = 16;  TC = 16; ch_base = 39;
        ooff = noise_base + (size_t)NB * T * 16;
    } else if (bid < 224) {               // stream 2: P=256, GZ=16
        bid -= 96;
        eps = eps2; P = 256;  PPv = 64;  TC = 32; ch_base = 42;
        ooff = noise_base + (size_t)NB * T * 80;
    } else {                              // stream 3: P=1024, GZ=64
        bid -= 224;
        eps = eps3; P = 1024; PPv = 256; TC = 32; ch_base = 45;
        ooff = noise_base + (size_t)NB * T * 336;
    }
    const int b    = bid % NB;
    const int gz   = bid / NB;
    const int pp   = tid % PPv;
    const int lane = tid / PPv;
    const int lanes = 256 / PPv;
    const int t0   = (gz * lanes + lane) * TC;
    const int p0   = pp * 4;

    // per-batch Gaussian weights
    float sigma = fmaxf(means[b * C_X + ch_base + 2], 0.001f);
    float inv2s2 = -0.5f / (sigma * sigma);
    float w[9];
    float wsum = 0.f;
    #pragma unroll
    for (int j = 0; j < 9; ++j) {
        float k = (float)(j - 4);
        w[j] = expf(k * k * inv2s2);
        wsum += w[j];
    }
    float winv = 1.0f / wsum;
    #pragma unroll
    for (int j = 0; j < 9; ++j) w[j] *= winv;

    auto raw4 = [&](int tt) -> f32x4 {
        if (tt < 0)  tt = -tt;                 // reflect (edge excluded)
        if (tt >= T) tt = 2 * T - 2 - tt;
        size_t row = (size_t)(b * T + tt);
        float mu = x[row * C_X + ch_base];
        float sg = x[row * C_X + ch_base + 1];
        f32x4 e = __builtin_nontemporal_load((const f32x4*)&eps[row * (size_t)P + p0]);
        return mu + sg * e;
    };

    f32x4 win[9];
    #pragma unroll
    for (int j = 0; j < 8; ++j) win[j + 1] = raw4(t0 - 4 + j);

    for (int t = t0; t < t0 + TC; ++t) {
        #pragma unroll
        for (int j = 0; j < 8; ++j) win[j] = win[j + 1];
        win[8] = raw4(t + 4);
        f32x4 acc = w[0] * win[0];
        #pragma unroll
        for (int j = 1; j < 9; ++j) acc += w[j] * win[j];
        __builtin_nontemporal_store(acc, (f32x4*)&out[ooff + (size_t)(b * T + t) * P + p0]);
    }
}

// ---------------------------------------------------------------------------
extern "C" void kernel_launch(void* const* d_in, const int* in_sizes, int n_in,
                              void* d_out, int out_size, void* d_ws, size_t ws_size,
                              hipStream_t stream) {
    const float* x     = (const float*)d_in[0];
    const float* table = (const float*)d_in[1];
    float* out   = (float*)d_out;
    float* means = (float*)d_ws;     // 8*48 floats

    const int B = NB, T = NT;

    // 1) time-means of all 48 channels
    means_kernel<<<B * C_X, 64, 0, stream>>>(x, means, T);

    // 2) everything else in one grid: 2304 lats blocks + 736 noise blocks
    const int TCHUNKS = T / TTL;
    const int nblk = B * 18 * TCHUNKS + 736;
    mega_kernel<<<nblk, 256, 0, stream>>>(x, table, means,
                                          (const float*)d_in[2], (const float*)d_in[3],
                                          (const float*)d_in[4], (const float*)d_in[5],
                                          out, T);
}